// Round 6
// baseline (115.894 us; speedup 1.0000x reference)
//
#include <hip/hip_runtime.h>
#include <cstdint>

#define BB   16
#define NN   1024
#define FIN  128
#define FOUT 64
#define ALPHA_S 0.2f
#define LOG2E 1.44269504f

typedef float    f32x4 __attribute__((ext_vector_type(4)));
typedef _Float16 half8 __attribute__((ext_vector_type(8)));
typedef _Float16 half4 __attribute__((ext_vector_type(4)));
typedef __fp16   pk2   __attribute__((ext_vector_type(2)));
typedef __fp16   pk4   __attribute__((ext_vector_type(4)));
typedef __fp16   pk8   __attribute__((ext_vector_type(8)));

__device__ __forceinline__ float fast_exp2(float x){
  float r; asm("v_exp_f32 %0, %1" : "=v"(r) : "v"(x)); return r;
}

// ---------------------------------------------------------------------------
// Kernel 1 (MFMA): h = inp @ W, f16 hi/lo 3-term MFMA (rel err ~2^-22).
// v2: 256 blocks x 4 row-tiles each.  W fragments (bh/bl, 32 VGPR) are
// loaded+split ONCE per block (was: once per 16-row tile = 4x the scalar-load
// instruction traffic).  inp for tile rt+1 is software-prefetched (double-
// buffered, static indices) before tile rt's MFMAs.  Epilogue red LDS is
// parity-double-buffered -> one barrier per tile.
// s1 = (h.a1)*log2e, s2 = (h.a2)*log2e; hT layout hT[b][j>>5][f][j&31].
// ---------------------------------------------------------------------------
__global__ __launch_bounds__(256) void k_proj(const float* __restrict__ inp,
                                              const float* __restrict__ W,
                                              const float* __restrict__ a,
                                              _Float16* __restrict__ hT,
                                              float* __restrict__ s1,
                                              float* __restrict__ s2){
  __shared__ float red1[2][4][16];
  __shared__ float red2[2][4][16];
  const int t = threadIdx.x;
  const int w = t >> 6, lane = t & 63;
  const int m16 = lane & 15, g = lane >> 4;
  const int bi0 = blockIdx.x * 64;         // this block's 64-row range
  const int b   = bi0 >> 10;
  const int c0  = w * 16;                  // this wave's col tile

  // ---- W fragments once per block: 32 scalar loads + hi/lo split ----
  half8 bhf[4], blf[4];
  #pragma unroll
  for (int kk = 0; kk < 4; ++kk){
    const int kbase = kk * 32 + g * 8;
    #pragma unroll
    for (int j = 0; j < 8; ++j){
      float wv = W[(kbase + j) * FOUT + c0 + m16];
      _Float16 h = (_Float16)wv;
      bhf[kk][j] = h;
      blf[kk][j] = (_Float16)(wv - (float)h);
    }
  }

  const float a1c = a[c0 + m16];
  const float a2c = a[FOUT + c0 + m16];

  // ---- prefetch row-tile 0 ----
  float4 pv0[2][4], pv1[2][4];
  {
    const float* ar = inp + (size_t)(bi0 + m16) * FIN;
    #pragma unroll
    for (int kk = 0; kk < 4; ++kk){
      pv0[0][kk] = *(const float4*)(ar + kk * 32 + g * 8);
      pv1[0][kk] = *(const float4*)(ar + kk * 32 + g * 8 + 4);
    }
  }

  #pragma unroll
  for (int rt = 0; rt < 4; ++rt){
    const int ph = rt & 1;
    const int i0 = bi0 + rt * 16;
    const int j0 = i0 & 1023;

    // prefetch next tile's inp before this tile's compute
    if (rt < 3){
      const float* ar = inp + (size_t)(i0 + 16 + m16) * FIN;
      #pragma unroll
      for (int kk = 0; kk < 4; ++kk){
        pv0[ph ^ 1][kk] = *(const float4*)(ar + kk * 32 + g * 8);
        pv1[ph ^ 1][kk] = *(const float4*)(ar + kk * 32 + g * 8 + 4);
      }
    }

    f32x4 acc = {0.f, 0.f, 0.f, 0.f};
    #pragma unroll
    for (int kk = 0; kk < 4; ++kk){
      const float4 a0 = pv0[ph][kk], a1 = pv1[ph][kk];
      const float av[8] = {a0.x, a0.y, a0.z, a0.w, a1.x, a1.y, a1.z, a1.w};
      half8 ah, al;
      #pragma unroll
      for (int j = 0; j < 8; ++j){
        _Float16 h = (_Float16)av[j];
        ah[j] = h;
        al[j] = (_Float16)(av[j] - (float)h);
      }
      acc = __builtin_amdgcn_mfma_f32_16x16x32_f16(ah, bhf[kk], acc, 0, 0, 0);
      acc = __builtin_amdgcn_mfma_f32_16x16x32_f16(ah, blf[kk], acc, 0, 0, 0);
      acc = __builtin_amdgcn_mfma_f32_16x16x32_f16(al, bhf[kk], acc, 0, 0, 0);
    }

    // ---- hT store (hi only): f = c0+m16, j = i0 + g*4 + q ----
    half4 hv;
    #pragma unroll
    for (int q = 0; q < 4; ++q) hv[q] = (_Float16)acc[q];
    size_t idx = (size_t)b * 65536 + (size_t)(j0 >> 5) * 2048
               + (size_t)(c0 + m16) * 32 + (size_t)(j0 & 31) + (size_t)g * 4;
    *(half4*)(hT + idx) = hv;

    // ---- s1/s2 partials: sum over this wave's 16 cols, rows g*4+q ----
    f32x4 p1, p2;
    #pragma unroll
    for (int q = 0; q < 4; ++q){ p1[q] = acc[q] * a1c; p2[q] = acc[q] * a2c; }
    #pragma unroll
    for (int off = 1; off < 16; off <<= 1){
      #pragma unroll
      for (int q = 0; q < 4; ++q){
        p1[q] += __shfl_xor(p1[q], off, 64);
        p2[q] += __shfl_xor(p2[q], off, 64);
      }
    }
    if (m16 == 0){
      #pragma unroll
      for (int q = 0; q < 4; ++q){
        red1[ph][w][g * 4 + q] = p1[q];
        red2[ph][w][g * 4 + q] = p2[q];
      }
    }
    __syncthreads();   // one barrier/tile: next tile writes the other parity
    if (t < 16){
      s1[i0 + t] = (red1[ph][0][t] + red1[ph][1][t]
                  + red1[ph][2][t] + red1[ph][3][t]) * LOG2E;
      s2[i0 + t] = (red2[ph][0][t] + red2[ph][1][t]
                  + red2[ph][2][t] + red2[ph][3][t]) * LOG2E;
    }
  }
}

// ---------------------------------------------------------------------------
// Kernel 2: fused GAT attention, barrier-free main body, low-VGPR variant.
// (unchanged from R5 -- best verified version)
// ---------------------------------------------------------------------------
__global__ __launch_bounds__(256, 4) void k_attn(const int* __restrict__ adj,
                                                 const _Float16* __restrict__ hT,
                                                 const float* __restrict__ s1,
                                                 const float* __restrict__ s2,
                                                 float* __restrict__ out){
  __shared__ float s2_s[NN];            // 4 KB
  __shared__ float redmax[4][16];
  __shared__ float redl[4][16];
  __shared__ float csum[4][1088];       // 4 x (16 rows x 68-pad) ~17 KB

  const int t = threadIdx.x;
  const int w = t >> 6, lane = t & 63;
  const int m16 = lane & 15, g = lane >> 4;
  const int b  = blockIdx.x >> 6;
  const int i0 = (blockIdx.x & 63) * 16;
  const int jb = w * 256;

  // stage this wave's s2 chunk (wave-internal lgkmcnt ordering; only this
  // wave reads its chunk, so no barrier needed before the LDS reads)
  *(float4*)&s2_s[jb + lane * 4] = *(const float4*)(s2 + b * NN + jb + lane * 4);

  // ---- adj burst: 16 int4 loads in flight; row i0+m16, cols jb+kk*32+g*8 ----
  const int* arow = adj + ((size_t)(b * NN + i0 + m16)) * NN + jb + g * 8;
  int4 A0[8], A1[8];
  #pragma unroll
  for (int kk = 0; kk < 8; ++kk){
    A0[kk] = *(const int4*)(arow + kk * 32);
    A1[kk] = *(const int4*)(arow + kk * 32 + 4);
  }

  const float s1i = s1[b * NN + i0 + m16];

  // ---- pass 1: bitmask (2 regs) + wave-local masked max of s2 ----
  unsigned mask_lo = 0u, mask_hi = 0u;
  float mxp = -3.0e38f;
  #pragma unroll
  for (int kk = 0; kk < 8; ++kk){
    float4 sA = *(const float4*)&s2_s[jb + kk * 32 + g * 8];
    float4 sB = *(const float4*)&s2_s[jb + kk * 32 + g * 8 + 4];
    unsigned bits = 0u;
    bits |= (A0[kk].x > 0) ? 1u   : 0u;  mxp = fmaxf(mxp, A0[kk].x > 0 ? sA.x : -3.0e38f);
    bits |= (A0[kk].y > 0) ? 2u   : 0u;  mxp = fmaxf(mxp, A0[kk].y > 0 ? sA.y : -3.0e38f);
    bits |= (A0[kk].z > 0) ? 4u   : 0u;  mxp = fmaxf(mxp, A0[kk].z > 0 ? sA.z : -3.0e38f);
    bits |= (A0[kk].w > 0) ? 8u   : 0u;  mxp = fmaxf(mxp, A0[kk].w > 0 ? sA.w : -3.0e38f);
    bits |= (A1[kk].x > 0) ? 16u  : 0u;  mxp = fmaxf(mxp, A1[kk].x > 0 ? sB.x : -3.0e38f);
    bits |= (A1[kk].y > 0) ? 32u  : 0u;  mxp = fmaxf(mxp, A1[kk].y > 0 ? sB.y : -3.0e38f);
    bits |= (A1[kk].z > 0) ? 64u  : 0u;  mxp = fmaxf(mxp, A1[kk].z > 0 ? sB.z : -3.0e38f);
    bits |= (A1[kk].w > 0) ? 128u : 0u;  mxp = fmaxf(mxp, A1[kk].w > 0 ? sB.w : -3.0e38f);
    if (kk < 4) mask_lo |= bits << (kk * 8);
    else        mask_hi |= bits << ((kk - 4) * 8);
  }

  // wave-local row max across the 4 lanes sharing m16 (no cross-wave barrier)
  mxp = fmaxf(mxp, __shfl_xor(mxp, 16, 64));
  mxp = fmaxf(mxp, __shfl_xor(mxp, 32, 64));
  mxp = fmaxf(mxp, -1.0e30f);                 // empty-row safe clamp
  const float xm   = s1i + mxp;
  const float mrow = fmaxf(xm, ALPHA_S * xm); // wave-local max of leaky (log2 dom)
  if (g == 0) redmax[w][m16] = mrow;
  const float s1m = s1i - mrow;
  const float c2  = ALPHA_S * s1i - mrow;

  // ---- pass 2: p from mask + LDS s2 -> 4 col-tile MFMAs (hi only) ----
  f32x4 acc0 = {0,0,0,0}, acc1 = {0,0,0,0}, acc2 = {0,0,0,0}, acc3 = {0,0,0,0};
  float psum = 0.f;
  const _Float16* bhp = hT + (size_t)b * 65536 + (size_t)(w * 8) * 2048
                      + (size_t)m16 * 32 + (size_t)g * 8;

  #pragma unroll
  for (int kk = 0; kk < 8; ++kk){
    float4 sA = *(const float4*)&s2_s[jb + kk * 32 + g * 8];
    float4 sB = *(const float4*)&s2_s[jb + kk * 32 + g * 8 + 4];
    const unsigned bits = (kk < 4) ? (mask_lo >> (kk * 8)) : (mask_hi >> ((kk - 4) * 8));
    const float sv[8] = {sA.x, sA.y, sA.z, sA.w, sB.x, sB.y, sB.z, sB.w};
    float p[8];
    #pragma unroll
    for (int u = 0; u < 8; ++u){
      float e = fast_exp2(fmaxf(s1m + sv[u], fmaf(ALPHA_S, sv[u], c2)));
      p[u] = ((bits >> u) & 1u) ? e : 0.0f;
    }
    psum += ((p[0] + p[1]) + (p[2] + p[3])) + ((p[4] + p[5]) + (p[6] + p[7]));

    pk2 q0 = __builtin_amdgcn_cvt_pkrtz(p[0], p[1]);
    pk2 q1 = __builtin_amdgcn_cvt_pkrtz(p[2], p[3]);
    pk2 q2 = __builtin_amdgcn_cvt_pkrtz(p[4], p[5]);
    pk2 q3 = __builtin_amdgcn_cvt_pkrtz(p[6], p[7]);
    pk4 l0 = __builtin_shufflevector(q0, q1, 0, 1, 2, 3);
    pk4 l1 = __builtin_shufflevector(q2, q3, 0, 1, 2, 3);
    half8 af = __builtin_bit_cast(half8,
                 __builtin_shufflevector(l0, l1, 0, 1, 2, 3, 4, 5, 6, 7));

    half8 b0 = *(const half8*)(bhp + kk * 2048);
    half8 b1 = *(const half8*)(bhp + kk * 2048 + 512);
    half8 b2 = *(const half8*)(bhp + kk * 2048 + 1024);
    half8 b3 = *(const half8*)(bhp + kk * 2048 + 1536);
    acc0 = __builtin_amdgcn_mfma_f32_16x16x32_f16(af, b0, acc0, 0, 0, 0);
    acc1 = __builtin_amdgcn_mfma_f32_16x16x32_f16(af, b1, acc1, 0, 0, 0);
    acc2 = __builtin_amdgcn_mfma_f32_16x16x32_f16(af, b2, acc2, 0, 0, 0);
    acc3 = __builtin_amdgcn_mfma_f32_16x16x32_f16(af, b3, acc3, 0, 0, 0);
  }

  // ---- epilogue: single barrier; flash-style cross-wave merge ----
  psum += __shfl_xor(psum, 16, 64);
  psum += __shfl_xor(psum, 32, 64);
  if (g == 0) redl[w][m16] = psum;

  #pragma unroll
  for (int q = 0; q < 4; ++q){                 // C: row = g*4+q, col = c*16+m16
    csum[w][(g * 4 + q) * 68 +  0 + m16] = acc0[q];
    csum[w][(g * 4 + q) * 68 + 16 + m16] = acc1[q];
    csum[w][(g * 4 + q) * 68 + 32 + m16] = acc2[q];
    csum[w][(g * 4 + q) * 68 + 48 + m16] = acc3[q];
  }
  __syncthreads();

  const int r  = t >> 4;                       // 0..15
  const int c4 = (t & 15) * 4;                 // 0..60
  const float m0 = redmax[0][r], m1 = redmax[1][r];
  const float m2 = redmax[2][r], m3 = redmax[3][r];
  const float mg = fmaxf(fmaxf(m0, m1), fmaxf(m2, m3));
  const float f0 = fast_exp2(m0 - mg), f1 = fast_exp2(m1 - mg);
  const float f2 = fast_exp2(m2 - mg), f3 = fast_exp2(m3 - mg);

  f32x4 c0v = *(const f32x4*)&csum[0][r * 68 + c4];
  f32x4 c1v = *(const f32x4*)&csum[1][r * 68 + c4];
  f32x4 c2v = *(const f32x4*)&csum[2][r * 68 + c4];
  f32x4 c3v = *(const f32x4*)&csum[3][r * 68 + c4];
  f32x4 sum;
  #pragma unroll
  for (int u = 0; u < 4; ++u)
    sum[u] = c0v[u] * f0 + c1v[u] * f1 + c2v[u] * f2 + c3v[u] * f3;

  const float l = redl[0][r] * f0 + redl[1][r] * f1
                + redl[2][r] * f2 + redl[3][r] * f3;
  const float linv = (l > 0.f) ? __builtin_amdgcn_rcpf(l) : 0.f;
  f32x4 o;
  #pragma unroll
  for (int u = 0; u < 4; ++u){
    float v = sum[u] * linv;
    o[u] = v > 0.f ? v : __expf(v) - 1.0f;     // ELU (alpha=1)
  }
  *(f32x4*)(out + ((size_t)(b * NN + i0 + r)) * FOUT + c4) = o;
}

extern "C" void kernel_launch(void* const* d_in, const int* in_sizes, int n_in,
                              void* d_out, int out_size, void* d_ws, size_t ws_size,
                              hipStream_t stream) {
  (void)in_sizes; (void)n_in; (void)out_size; (void)ws_size;
  const float* inp = (const float*)d_in[0];   // (16,1024,128) fp32
  const int*   adj = (const int*)d_in[1];     // (16,1024,1024) int32
  const float* W   = (const float*)d_in[2];   // (128,64) fp32
  const float* a   = (const float*)d_in[3];   // (128,1) fp32
  float* outp = (float*)d_out;                // (16,1024,64) fp32

  _Float16* hT = (_Float16*)d_ws;                      // 2 MB (hi only)
  float* s1 = (float*)(hT + (size_t)BB * 65536);       // 64 KB
  float* s2 = s1 + BB * NN;                            // 64 KB

  k_proj<<<BB * NN / 64, 256, 0, stream>>>(inp, W, a, hT, s1, s2);
  k_attn<<<BB * (NN / 16), 256, 0, stream>>>(adj, hT, s1, s2, outp);
}